// Round 4
// baseline (276.718 us; speedup 1.0000x reference)
//
#include <hip/hip_runtime.h>

#define NB 8
#define NS 4096
#define ND 768
#define NT 32768   // NB*NS

typedef float4 f4;
typedef __attribute__((ext_vector_type(8))) short short8;
typedef __attribute__((ext_vector_type(4))) float floatx4;
typedef unsigned short ushort_t;
typedef unsigned int uint_t;

static __device__ __forceinline__ ushort_t f2b(float f) {   // f32 -> bf16 RNE
    union { float f; uint_t u; } v; v.f = f;
    uint_t r = (v.u + 0x7FFFu + ((v.u >> 16) & 1u)) >> 16;
    return (ushort_t)r;
}
static __device__ __forceinline__ float b2f(ushort_t s) {
    union { uint_t u; float f; } v; v.u = ((uint_t)s) << 16;
    return v.f;
}
static __device__ __forceinline__ f4 ld4(const float* p) { return *(const f4*)p; }

// ---------------------------------------------------------------------------
// K1: zero d_out; scatter-max parent table; per-batch style projection.
// table pre-memset to -1, cnt pre-memset to 0 (host side, async).
// ---------------------------------------------------------------------------
__global__ __launch_bounds__(256) void k1(
    const int* __restrict__ et, const int* __restrict__ ei,
    const float* __restrict__ sv, const float* __restrict__ sw,
    const float* __restrict__ sb,
    int* __restrict__ table, float* __restrict__ sprj, float* __restrict__ out)
{
    const int tid = blockIdx.x * 256 + threadIdx.x;   // 0..33279
    for (int i = tid; i < 163840; i += 33280)         // zero 655360 f32
        ((f4*)out)[i] = make_float4(0.f, 0.f, 0.f, 0.f);

    if (blockIdx.x < 128) {
        // scatter-max: last panel occurrence wins (== ref's scatter-max over kept)
        if (et[tid] == 1)
            atomicMax(&table[(tid >> 12) * 64 + ei[tid]], tid & (NS - 1));
    } else {
        const int lane = threadIdx.x & 63;
        const int b = (blockIdx.x - 128) * 4 + (threadIdx.x >> 6);  // 0..7
        const float s0 = sv[b*4+0], s1 = sv[b*4+1], s2 = sv[b*4+2], s3 = sv[b*4+3];
        #pragma unroll
        for (int g = 0; g < 3; ++g) {
            int i = g*64 + lane;
            f4 w0 = ((const f4*)sw)[i],       w1 = ((const f4*)sw)[192+i];
            f4 w2 = ((const f4*)sw)[384+i],   w3 = ((const f4*)sw)[576+i];
            f4 bb = ((const f4*)sb)[i];
            f4 r;
            r.x = bb.x + s0*w0.x + s1*w1.x + s2*w2.x + s3*w3.x;
            r.y = bb.y + s0*w0.y + s1*w1.y + s2*w2.y + s3*w3.y;
            r.z = bb.z + s0*w0.z + s1*w1.z + s2*w2.z + s3*w3.z;
            r.w = bb.w + s0*w0.w + s1*w1.w + s2*w2.w + s3*w3.w;
            ((f4*)(sprj + b*ND))[i] = r;
        }
    }
}

// ---------------------------------------------------------------------------
// K2: blocks 0..127  : parent panel feats (LN'd) -> pfeat[b*64+slot] as bf16
//     blocks 128..255: build per-type token lists (validity folded in)
// ---------------------------------------------------------------------------
__global__ __launch_bounds__(256) void k2(
    const int* __restrict__ et, const int* __restrict__ ei, const int* __restrict__ ppi,
    const float* __restrict__ temb, const float* __restrict__ iemb,
    const float* __restrict__ pemb, const float* __restrict__ lng,
    const float* __restrict__ lnb,
    const int* __restrict__ table, const float* __restrict__ sprj,
    ushort_t* __restrict__ pfeat, int* __restrict__ cnt, int* __restrict__ lists)
{
    if (blockIdx.x < 128) {
        const int lane = threadIdx.x & 63;
        const int slot = blockIdx.x * 4 + (threadIdx.x >> 6);   // 0..511
        const int pp = table[slot];
        if (pp < 0) return;                                     // wave-uniform
        const int b = slot >> 6;
        const int ptok = b * NS + pp;
        const float* ie = iemb + ei[ptok] * ND;
        const float* pe = pemb + ppi[ptok] * ND;
        const float* sp = sprj + b * ND;

        f4 x[3]; float s1 = 0.f;
        #pragma unroll
        for (int g = 0; g < 3; ++g) {
            int i = g*64 + lane;
            f4 a = ((const f4*)(temb + ND))[i], c = ((const f4*)ie)[i];
            f4 d = ((const f4*)pe)[i],          s = ((const f4*)sp)[i];
            x[g].x = a.x + c.x + d.x + s.x;
            x[g].y = a.y + c.y + d.y + s.y;
            x[g].z = a.z + c.z + d.z + s.z;
            x[g].w = a.w + c.w + d.w + s.w;
            s1 += x[g].x + x[g].y + x[g].z + x[g].w;
        }
        #pragma unroll
        for (int o = 1; o < 64; o <<= 1) s1 += __shfl_xor(s1, o, 64);
        float mu = s1 * (1.f/ND);
        float s2 = 0.f;
        #pragma unroll
        for (int g = 0; g < 3; ++g) {
            float dx = x[g].x-mu, dy = x[g].y-mu, dz = x[g].z-mu, dw_ = x[g].w-mu;
            s2 += dx*dx + dy*dy + dz*dz + dw_*dw_;
        }
        #pragma unroll
        for (int o = 1; o < 64; o <<= 1) s2 += __shfl_xor(s2, o, 64);
        float rs = rsqrtf(s2 * (1.f/ND) + 1e-5f);
        ushort_t* dst = pfeat + (size_t)slot * ND;
        #pragma unroll
        for (int g = 0; g < 3; ++g) {
            int i = g*64 + lane;
            f4 gg = ((const f4*)lng)[i], bb = ((const f4*)lnb)[i];
            ushort_t r0 = f2b((x[g].x-mu)*rs*gg.x + bb.x);
            ushort_t r1 = f2b((x[g].y-mu)*rs*gg.y + bb.y);
            ushort_t r2 = f2b((x[g].z-mu)*rs*gg.z + bb.z);
            ushort_t r3 = f2b((x[g].w-mu)*rs*gg.w + bb.w);
            *(uint2*)(dst + 4*i) = make_uint2((uint_t)r0 | ((uint_t)r1 << 16),
                                              (uint_t)r2 | ((uint_t)r3 << 16));
        }
    } else {
        const int t = (blockIdx.x - 128) * 256 + threadIdx.x;
        const int ty = et[t];
        if (ty == 1) {
            int idx = atomicAdd(&cnt[0], 1);
            lists[idx] = t;
        } else if (ty >= 2) {
            if (table[(t >> 12) * 64 + ppi[t]] >= 0) {
                int idx = atomicAdd(&cnt[ty-1], 1);
                lists[(ty-1) * NT + idx] = t;
            }
        }
    }
}

// ---------------------------------------------------------------------------
// K3: MFMA head kernels. blockIdx>>9 = type-1; 64 tokens/block, 16/wave.
// B (weights, zero-padded to N=16) pre-swizzled into LDS as frag-major bf16.
// A fragments built on the fly: fused embedding-sum + LN in MFMA A-layout.
// ---------------------------------------------------------------------------
__global__ __launch_bounds__(256) void k3(
    const int* __restrict__ ei, const int* __restrict__ ppi,
    const float* __restrict__ temb, const float* __restrict__ iemb,
    const float* __restrict__ pemb, const float* __restrict__ lng,
    const float* __restrict__ lnb,
    const float* __restrict__ pw, const float* __restrict__ pb,
    const float* __restrict__ dw, const float* __restrict__ db,
    const float* __restrict__ cw, const float* __restrict__ cb,
    const float* __restrict__ sprj, const ushort_t* __restrict__ pfeat,
    const int* __restrict__ cnt, const int* __restrict__ lists,
    float* __restrict__ out)
{
    __shared__ uint4 bbuf[48 * 64];                  // 48 KB: B fragments
    const int ty = (blockIdx.x >> 9) + 1;            // 1,2,3 (wave-uniform)
    const int chunk = blockIdx.x & 511;
    const int cn = cnt[ty - 1];
    if (chunk * 64 >= cn) return;

    const int W = (ty == 3) ? 4 : 8;
    const int wsh = (ty == 3) ? 2 : 3;
    const int Ktot = (ty == 1) ? 768 : 1536;
    const float* wsrc = (ty == 1) ? pw : (ty == 2) ? dw : cw;
    const float* bias = (ty == 1) ? pb : (ty == 2) ? db : cb;
    const int* list = lists + (ty - 1) * NT;

    // ---- stage B into LDS (zero-pad cols W..15), frag-major layout ----
    const int nq = (Ktot / 32) * 64;                 // 1536 or 3072 uint4
    for (int i = threadIdx.x; i < nq; i += 256)
        bbuf[i] = make_uint4(0u, 0u, 0u, 0u);
    __syncthreads();
    {
        const int f4n = (Ktot * W) / 4;              // 1536/3072/1536
        for (int i = threadIdx.x; i < f4n; i += 256) {
            f4 v = ((const f4*)wsrc)[i];
            #pragma unroll
            for (int q = 0; q < 4; ++q) {
                int e = 4*i + q;
                int k = e >> wsh, n = e & (W - 1);
                int l = (((k >> 3) & 3) << 4) + n;   // lane: n=l&15, kquad=l>>4
                int s = k >> 5, j = k & 7;
                float val = (q == 0) ? v.x : (q == 1) ? v.y : (q == 2) ? v.z : v.w;
                ((ushort_t*)bbuf)[(s*64 + l)*8 + j] = f2b(val);
            }
        }
    }
    __syncthreads();

    // ---- per-wave 16-token tile ----
    const int lane = threadIdx.x & 63;
    const int gbase = chunk * 64 + (threadIdx.x >> 6) * 16;
    if (gbase >= cn) return;
    const int m = lane & 15;                         // token within tile (A row)
    const int koff = (lane >> 4) * 8;                // k-chunk base
    const int slot = min(gbase + m, cn - 1);
    const int tl = list[slot];
    const int b = tl >> 12;
    const int eidx = ei[tl], pidx = ppi[tl];
    const float* ie_p = iemb + eidx * ND;
    const float* pe_p = pemb + pidx * ND;
    const float* sp_p = sprj + b * ND;
    const float* te_p = temb + ty * ND;

    // pass 1: x = te + ie + pe + sproj, stats + bf16-packed x
    short8 xf[24];
    float sum = 0.f, sq = 0.f;
    #pragma unroll
    for (int s = 0; s < 24; ++s) {
        int d0 = 32*s + koff;
        f4 a0 = ld4(te_p + d0), a1 = ld4(te_p + d0 + 4);
        f4 c0 = ld4(ie_p + d0), c1 = ld4(ie_p + d0 + 4);
        f4 e0 = ld4(pe_p + d0), e1 = ld4(pe_p + d0 + 4);
        f4 p0 = ld4(sp_p + d0), p1 = ld4(sp_p + d0 + 4);
        float x0 = a0.x + c0.x + e0.x + p0.x;
        float x1 = a0.y + c0.y + e0.y + p0.y;
        float x2 = a0.z + c0.z + e0.z + p0.z;
        float x3 = a0.w + c0.w + e0.w + p0.w;
        float x4 = a1.x + c1.x + e1.x + p1.x;
        float x5 = a1.y + c1.y + e1.y + p1.y;
        float x6 = a1.z + c1.z + e1.z + p1.z;
        float x7 = a1.w + c1.w + e1.w + p1.w;
        sum += (x0+x1)+(x2+x3)+(x4+x5)+(x6+x7);
        sq  += (x0*x0+x1*x1)+(x2*x2+x3*x3)+(x4*x4+x5*x5)+(x6*x6+x7*x7);
        short8 t8;
        t8[0]=(short)f2b(x0); t8[1]=(short)f2b(x1); t8[2]=(short)f2b(x2); t8[3]=(short)f2b(x3);
        t8[4]=(short)f2b(x4); t8[5]=(short)f2b(x5); t8[6]=(short)f2b(x6); t8[7]=(short)f2b(x7);
        xf[s] = t8;
    }
    // reduce stats across the 4 k-groups of this token (lanes m, m+16, m+32, m+48)
    sum += __shfl_xor(sum, 16, 64); sum += __shfl_xor(sum, 32, 64);
    sq  += __shfl_xor(sq , 16, 64); sq  += __shfl_xor(sq , 32, 64);
    float mu = sum * (1.f/ND);
    float rs = rsqrtf(sq * (1.f/ND) - mu*mu + 1e-5f);

    // pass 2: LN-apply per fragment, MFMA against staged B
    floatx4 acc = {0.f, 0.f, 0.f, 0.f};
    #pragma unroll
    for (int s = 0; s < 24; ++s) {
        int d0 = 32*s + koff;
        f4 g0 = ld4(lng + d0), g1 = ld4(lng + d0 + 4);
        f4 h0 = ld4(lnb + d0), h1 = ld4(lnb + d0 + 4);
        short8 ff;
        ff[0] = (short)f2b((b2f((ushort_t)xf[s][0]) - mu)*rs*g0.x + h0.x);
        ff[1] = (short)f2b((b2f((ushort_t)xf[s][1]) - mu)*rs*g0.y + h0.y);
        ff[2] = (short)f2b((b2f((ushort_t)xf[s][2]) - mu)*rs*g0.z + h0.z);
        ff[3] = (short)f2b((b2f((ushort_t)xf[s][3]) - mu)*rs*g0.w + h0.w);
        ff[4] = (short)f2b((b2f((ushort_t)xf[s][4]) - mu)*rs*g1.x + h1.x);
        ff[5] = (short)f2b((b2f((ushort_t)xf[s][5]) - mu)*rs*g1.y + h1.y);
        ff[6] = (short)f2b((b2f((ushort_t)xf[s][6]) - mu)*rs*g1.z + h1.z);
        ff[7] = (short)f2b((b2f((ushort_t)xf[s][7]) - mu)*rs*g1.w + h1.w);
        short8 bf = ((short8*)bbuf)[s*64 + lane];
        acc = __builtin_amdgcn_mfma_f32_16x16x32_bf16(ff, bf, acc, 0, 0, 0);
    }
    if (ty != 1) {
        // second K-half: parent feats (already LN'd bf16) @ lower weight rows
        const ushort_t* pf_p = pfeat + (size_t)(b*64 + pidx) * ND;
        #pragma unroll
        for (int s = 0; s < 24; ++s) {
            short8 af = *(const short8*)(pf_p + 32*s + koff);
            short8 bf = ((short8*)bbuf)[(24 + s)*64 + lane];
            acc = __builtin_amdgcn_mfma_f32_16x16x32_bf16(af, bf, acc, 0, 0, 0);
        }
    }

    // ---- epilogue: D lane holds col n=lane&15, rows (lane>>4)*4+r ----
    const int n = lane & 15;
    const float bv = (n < W) ? bias[n] : 0.f;
    const long obase = (ty == 1) ? 0L : (ty == 2) ? (long)NT*8 : (long)NT*16;
    #pragma unroll
    for (int r = 0; r < 4; ++r) {
        int row = (lane >> 4) * 4 + r;
        int rslot = gbase + row;
        if (n < W && rslot < cn) {
            int tr = list[rslot];
            out[obase + (long)tr * W + n] = acc[r] + bv;
        }
    }
}

extern "C" void kernel_launch(void* const* d_in, const int* in_sizes, int n_in,
                              void* d_out, int out_size, void* d_ws, size_t ws_size,
                              hipStream_t stream) {
    const int* et  = (const int*)d_in[0];
    const int* ei  = (const int*)d_in[1];
    const int* ppi = (const int*)d_in[2];
    const float* sv   = (const float*)d_in[3];
    const float* temb = (const float*)d_in[4];
    const float* iemb = (const float*)d_in[5];
    const float* pemb = (const float*)d_in[6];
    const float* sw   = (const float*)d_in[7];
    const float* sb   = (const float*)d_in[8];
    const float* lng  = (const float*)d_in[9];
    const float* lnb  = (const float*)d_in[10];
    const float* pw   = (const float*)d_in[11];
    const float* pb   = (const float*)d_in[12];
    const float* dw   = (const float*)d_in[13];
    const float* db   = (const float*)d_in[14];
    const float* cw   = (const float*)d_in[15];
    const float* cbp  = (const float*)d_in[16];
    float* out = (float*)d_out;

    // ws: table@0 (2KB) | cnt@2048 (12B) | sprj@4096 (24KB f32)
    //     pfeat@28672 (512x768 bf16 = 768KB) | lists@815104 (3x32768 int = 384KB)
    int*      table = (int*)d_ws;
    int*      cnt   = (int*)((char*)d_ws + 2048);
    float*    sprj  = (float*)((char*)d_ws + 4096);
    ushort_t* pfeat = (ushort_t*)((char*)d_ws + 28672);
    int*      lists = (int*)((char*)d_ws + 815104);

    hipMemsetAsync(table, 0xFF, 512 * sizeof(int), stream);   // all -1
    hipMemsetAsync(cnt, 0x00, 3 * sizeof(int), stream);

    k1<<<130, 256, 0, stream>>>(et, ei, sv, sw, sb, table, sprj, out);
    k2<<<256, 256, 0, stream>>>(et, ei, ppi, temb, iemb, pemb, lng, lnb,
                                table, sprj, pfeat, cnt, lists);
    k3<<<1536, 256, 0, stream>>>(ei, ppi, temb, iemb, pemb, lng, lnb,
                                 pw, pb, dw, db, cw, cbp, sprj, pfeat,
                                 cnt, lists, out);
}

// Round 5
// 157.000 us; speedup vs baseline: 1.7625x; 1.7625x over previous
//
#include <hip/hip_runtime.h>

#define NB 8
#define NS 4096
#define ND 768
#define NT 32768   // NB*NS

typedef float4 f4;
typedef __attribute__((ext_vector_type(8))) short short8;
typedef __attribute__((ext_vector_type(4))) float floatx4;
typedef unsigned short ushort_t;
typedef unsigned int uint_t;

static __device__ __forceinline__ ushort_t f2b(float f) {   // f32 -> bf16 RNE
    union { float f; uint_t u; } v; v.f = f;
    uint_t r = (v.u + 0x7FFFu + ((v.u >> 16) & 1u)) >> 16;
    return (ushort_t)r;
}
static __device__ __forceinline__ float b2f(ushort_t s) {
    union { uint_t u; float f; } v; v.u = ((uint_t)s) << 16;
    return v.f;
}
static __device__ __forceinline__ f4 ld4(const float* p) { return *(const f4*)p; }

// ---------------------------------------------------------------------------
// K1: zero d_out; scatter-max parent table; per-batch style projection.
// ---------------------------------------------------------------------------
__global__ __launch_bounds__(256) void k1(
    const int* __restrict__ et, const int* __restrict__ ei,
    const float* __restrict__ sv, const float* __restrict__ sw,
    const float* __restrict__ sb,
    int* __restrict__ table, float* __restrict__ sprj, float* __restrict__ out)
{
    const int tid = blockIdx.x * 256 + threadIdx.x;   // 0..33279
    for (int i = tid; i < 163840; i += 33280)         // zero 655360 f32
        ((f4*)out)[i] = make_float4(0.f, 0.f, 0.f, 0.f);

    if (blockIdx.x < 128) {
        // scatter-max: last panel occurrence wins (== ref's scatter-max over kept)
        if (et[tid] == 1)
            atomicMax(&table[(tid >> 12) * 64 + ei[tid]], tid & (NS - 1));
    } else {
        const int lane = threadIdx.x & 63;
        const int b = (blockIdx.x - 128) * 4 + (threadIdx.x >> 6);  // 0..7
        const float s0 = sv[b*4+0], s1 = sv[b*4+1], s2 = sv[b*4+2], s3 = sv[b*4+3];
        #pragma unroll
        for (int g = 0; g < 3; ++g) {
            int i = g*64 + lane;
            f4 w0 = ((const f4*)sw)[i],       w1 = ((const f4*)sw)[192+i];
            f4 w2 = ((const f4*)sw)[384+i],   w3 = ((const f4*)sw)[576+i];
            f4 bb = ((const f4*)sb)[i];
            f4 r;
            r.x = bb.x + s0*w0.x + s1*w1.x + s2*w2.x + s3*w3.x;
            r.y = bb.y + s0*w0.y + s1*w1.y + s2*w2.y + s3*w3.y;
            r.z = bb.z + s0*w0.z + s1*w1.z + s2*w2.z + s3*w3.z;
            r.w = bb.w + s0*w0.w + s1*w1.w + s2*w2.w + s3*w3.w;
            ((f4*)(sprj + b*ND))[i] = r;
        }
    }
}

// ---------------------------------------------------------------------------
// K2: blocks 0..127  : parent panel feats (LN'd) -> pfeat[b*64+slot] as bf16
//     blocks 128..255: per-type token lists, WAVE-AGGREGATED atomics
//     (per-lane atomicAdd on 3 shared addresses serialized at ~13.5 cyc each
//      = 137 us in R4; ballot + one leader atomic per wave per type fixes it)
// ---------------------------------------------------------------------------
__global__ __launch_bounds__(256) void k2(
    const int* __restrict__ et, const int* __restrict__ ei, const int* __restrict__ ppi,
    const float* __restrict__ temb, const float* __restrict__ iemb,
    const float* __restrict__ pemb, const float* __restrict__ lng,
    const float* __restrict__ lnb,
    const int* __restrict__ table, const float* __restrict__ sprj,
    ushort_t* __restrict__ pfeat, int* __restrict__ cnt, int* __restrict__ lists)
{
    if (blockIdx.x < 128) {
        const int lane = threadIdx.x & 63;
        const int slot = blockIdx.x * 4 + (threadIdx.x >> 6);   // 0..511
        const int pp = table[slot];
        if (pp < 0) return;                                     // wave-uniform
        const int b = slot >> 6;
        const int ptok = b * NS + pp;
        const float* ie = iemb + ei[ptok] * ND;
        const float* pe = pemb + ppi[ptok] * ND;
        const float* sp = sprj + b * ND;

        f4 x[3]; float s1 = 0.f;
        #pragma unroll
        for (int g = 0; g < 3; ++g) {
            int i = g*64 + lane;
            f4 a = ((const f4*)(temb + ND))[i], c = ((const f4*)ie)[i];
            f4 d = ((const f4*)pe)[i],          s = ((const f4*)sp)[i];
            x[g].x = a.x + c.x + d.x + s.x;
            x[g].y = a.y + c.y + d.y + s.y;
            x[g].z = a.z + c.z + d.z + s.z;
            x[g].w = a.w + c.w + d.w + s.w;
            s1 += x[g].x + x[g].y + x[g].z + x[g].w;
        }
        #pragma unroll
        for (int o = 1; o < 64; o <<= 1) s1 += __shfl_xor(s1, o, 64);
        float mu = s1 * (1.f/ND);
        float s2 = 0.f;
        #pragma unroll
        for (int g = 0; g < 3; ++g) {
            float dx = x[g].x-mu, dy = x[g].y-mu, dz = x[g].z-mu, dw_ = x[g].w-mu;
            s2 += dx*dx + dy*dy + dz*dz + dw_*dw_;
        }
        #pragma unroll
        for (int o = 1; o < 64; o <<= 1) s2 += __shfl_xor(s2, o, 64);
        float rs = rsqrtf(s2 * (1.f/ND) + 1e-5f);
        ushort_t* dst = pfeat + (size_t)slot * ND;
        #pragma unroll
        for (int g = 0; g < 3; ++g) {
            int i = g*64 + lane;
            f4 gg = ((const f4*)lng)[i], bb = ((const f4*)lnb)[i];
            ushort_t r0 = f2b((x[g].x-mu)*rs*gg.x + bb.x);
            ushort_t r1 = f2b((x[g].y-mu)*rs*gg.y + bb.y);
            ushort_t r2 = f2b((x[g].z-mu)*rs*gg.z + bb.z);
            ushort_t r3 = f2b((x[g].w-mu)*rs*gg.w + bb.w);
            *(uint2*)(dst + 4*i) = make_uint2((uint_t)r0 | ((uint_t)r1 << 16),
                                              (uint_t)r2 | ((uint_t)r3 << 16));
        }
    } else {
        const int t = (blockIdx.x - 128) * 256 + threadIdx.x;
        const int lane = threadIdx.x & 63;
        const int ty = et[t];
        const bool vld = (ty >= 2) && (table[(t >> 12) * 64 + ppi[t]] >= 0);
        #pragma unroll
        for (int i = 1; i <= 3; ++i) {
            bool p = (i == 1) ? (ty == 1) : (ty == i && vld);
            unsigned long long mask = __ballot(p);
            if (mask == 0ull) continue;
            int leader = __ffsll((long long)mask) - 1;
            int base = 0;
            if (lane == leader)
                base = atomicAdd(&cnt[i - 1], __popcll(mask));
            base = __shfl(base, leader, 64);
            if (p) {
                int prefix = __popcll(mask & ((1ull << lane) - 1ull));
                lists[(i - 1) * NT + base + prefix] = t;
            }
        }
    }
}

// ---------------------------------------------------------------------------
// K3: MFMA head kernels. blockIdx>>9 = type-1; 64 tokens/block, 16/wave.
// B (weights, zero-padded to N=16) pre-swizzled into LDS as frag-major bf16.
// A fragments built on the fly: fused embedding-sum + LN in MFMA A-layout.
// ---------------------------------------------------------------------------
__global__ __launch_bounds__(256) void k3(
    const int* __restrict__ ei, const int* __restrict__ ppi,
    const float* __restrict__ temb, const float* __restrict__ iemb,
    const float* __restrict__ pemb, const float* __restrict__ lng,
    const float* __restrict__ lnb,
    const float* __restrict__ pw, const float* __restrict__ pb,
    const float* __restrict__ dw, const float* __restrict__ db,
    const float* __restrict__ cw, const float* __restrict__ cb,
    const float* __restrict__ sprj, const ushort_t* __restrict__ pfeat,
    const int* __restrict__ cnt, const int* __restrict__ lists,
    float* __restrict__ out)
{
    __shared__ uint4 bbuf[48 * 64];                  // 48 KB: B fragments
    const int ty = (blockIdx.x >> 9) + 1;            // 1,2,3 (wave-uniform)
    const int chunk = blockIdx.x & 511;
    const int cn = cnt[ty - 1];
    if (chunk * 64 >= cn) return;

    const int W = (ty == 3) ? 4 : 8;
    const int wsh = (ty == 3) ? 2 : 3;
    const int Ktot = (ty == 1) ? 768 : 1536;
    const float* wsrc = (ty == 1) ? pw : (ty == 2) ? dw : cw;
    const float* bias = (ty == 1) ? pb : (ty == 2) ? db : cb;
    const int* list = lists + (ty - 1) * NT;

    // ---- stage B into LDS (zero-pad cols W..15), frag-major layout ----
    const int nq = (Ktot / 32) * 64;                 // 1536 or 3072 uint4
    for (int i = threadIdx.x; i < nq; i += 256)
        bbuf[i] = make_uint4(0u, 0u, 0u, 0u);
    __syncthreads();
    {
        const int f4n = (Ktot * W) / 4;              // 1536/3072/1536
        for (int i = threadIdx.x; i < f4n; i += 256) {
            f4 v = ((const f4*)wsrc)[i];
            #pragma unroll
            for (int q = 0; q < 4; ++q) {
                int e = 4*i + q;
                int k = e >> wsh, n = e & (W - 1);
                int l = (((k >> 3) & 3) << 4) + n;   // lane: n=l&15, kquad=l>>4
                int s = k >> 5, j = k & 7;
                float val = (q == 0) ? v.x : (q == 1) ? v.y : (q == 2) ? v.z : v.w;
                ((ushort_t*)bbuf)[(s*64 + l)*8 + j] = f2b(val);
            }
        }
    }
    __syncthreads();

    // ---- per-wave 16-token tile ----
    const int lane = threadIdx.x & 63;
    const int gbase = chunk * 64 + (threadIdx.x >> 6) * 16;
    if (gbase >= cn) return;
    const int m = lane & 15;                         // token within tile (A row)
    const int koff = (lane >> 4) * 8;                // k-chunk base
    const int slot = min(gbase + m, cn - 1);
    const int tl = list[slot];
    const int b = tl >> 12;
    const int eidx = ei[tl], pidx = ppi[tl];
    const float* ie_p = iemb + eidx * ND;
    const float* pe_p = pemb + pidx * ND;
    const float* sp_p = sprj + b * ND;
    const float* te_p = temb + ty * ND;

    // pass 1: x = te + ie + pe + sproj, stats + bf16-packed x
    short8 xf[24];
    float sum = 0.f, sq = 0.f;
    #pragma unroll
    for (int s = 0; s < 24; ++s) {
        int d0 = 32*s + koff;
        f4 a0 = ld4(te_p + d0), a1 = ld4(te_p + d0 + 4);
        f4 c0 = ld4(ie_p + d0), c1 = ld4(ie_p + d0 + 4);
        f4 e0 = ld4(pe_p + d0), e1 = ld4(pe_p + d0 + 4);
        f4 p0 = ld4(sp_p + d0), p1 = ld4(sp_p + d0 + 4);
        float x0 = a0.x + c0.x + e0.x + p0.x;
        float x1 = a0.y + c0.y + e0.y + p0.y;
        float x2 = a0.z + c0.z + e0.z + p0.z;
        float x3 = a0.w + c0.w + e0.w + p0.w;
        float x4 = a1.x + c1.x + e1.x + p1.x;
        float x5 = a1.y + c1.y + e1.y + p1.y;
        float x6 = a1.z + c1.z + e1.z + p1.z;
        float x7 = a1.w + c1.w + e1.w + p1.w;
        sum += (x0+x1)+(x2+x3)+(x4+x5)+(x6+x7);
        sq  += (x0*x0+x1*x1)+(x2*x2+x3*x3)+(x4*x4+x5*x5)+(x6*x6+x7*x7);
        short8 t8;
        t8[0]=(short)f2b(x0); t8[1]=(short)f2b(x1); t8[2]=(short)f2b(x2); t8[3]=(short)f2b(x3);
        t8[4]=(short)f2b(x4); t8[5]=(short)f2b(x5); t8[6]=(short)f2b(x6); t8[7]=(short)f2b(x7);
        xf[s] = t8;
    }
    // reduce stats across the 4 k-groups of this token (lanes m, m+16, m+32, m+48)
    sum += __shfl_xor(sum, 16, 64); sum += __shfl_xor(sum, 32, 64);
    sq  += __shfl_xor(sq , 16, 64); sq  += __shfl_xor(sq , 32, 64);
    float mu = sum * (1.f/ND);
    float rs = rsqrtf(sq * (1.f/ND) - mu*mu + 1e-5f);

    // pass 2: LN-apply per fragment, MFMA against staged B
    floatx4 acc = {0.f, 0.f, 0.f, 0.f};
    #pragma unroll
    for (int s = 0; s < 24; ++s) {
        int d0 = 32*s + koff;
        f4 g0 = ld4(lng + d0), g1 = ld4(lng + d0 + 4);
        f4 h0 = ld4(lnb + d0), h1 = ld4(lnb + d0 + 4);
        short8 ff;
        ff[0] = (short)f2b((b2f((ushort_t)xf[s][0]) - mu)*rs*g0.x + h0.x);
        ff[1] = (short)f2b((b2f((ushort_t)xf[s][1]) - mu)*rs*g0.y + h0.y);
        ff[2] = (short)f2b((b2f((ushort_t)xf[s][2]) - mu)*rs*g0.z + h0.z);
        ff[3] = (short)f2b((b2f((ushort_t)xf[s][3]) - mu)*rs*g0.w + h0.w);
        ff[4] = (short)f2b((b2f((ushort_t)xf[s][4]) - mu)*rs*g1.x + h1.x);
        ff[5] = (short)f2b((b2f((ushort_t)xf[s][5]) - mu)*rs*g1.y + h1.y);
        ff[6] = (short)f2b((b2f((ushort_t)xf[s][6]) - mu)*rs*g1.z + h1.z);
        ff[7] = (short)f2b((b2f((ushort_t)xf[s][7]) - mu)*rs*g1.w + h1.w);
        short8 bf = ((short8*)bbuf)[s*64 + lane];
        acc = __builtin_amdgcn_mfma_f32_16x16x32_bf16(ff, bf, acc, 0, 0, 0);
    }
    if (ty != 1) {
        // second K-half: parent feats (already LN'd bf16) @ lower weight rows
        const ushort_t* pf_p = pfeat + (size_t)(b*64 + pidx) * ND;
        #pragma unroll
        for (int s = 0; s < 24; ++s) {
            short8 af = *(const short8*)(pf_p + 32*s + koff);
            short8 bf = ((short8*)bbuf)[(24 + s)*64 + lane];
            acc = __builtin_amdgcn_mfma_f32_16x16x32_bf16(af, bf, acc, 0, 0, 0);
        }
    }

    // ---- epilogue: D lane holds col n=lane&15, rows (lane>>4)*4+r ----
    const int n = lane & 15;
    const float bv = (n < W) ? bias[n] : 0.f;
    const long obase = (ty == 1) ? 0L : (ty == 2) ? (long)NT*8 : (long)NT*16;
    #pragma unroll
    for (int r = 0; r < 4; ++r) {
        int row = (lane >> 4) * 4 + r;
        int rslot = gbase + row;
        if (n < W && rslot < cn) {
            int tr = list[rslot];
            out[obase + (long)tr * W + n] = acc[r] + bv;
        }
    }
}

extern "C" void kernel_launch(void* const* d_in, const int* in_sizes, int n_in,
                              void* d_out, int out_size, void* d_ws, size_t ws_size,
                              hipStream_t stream) {
    const int* et  = (const int*)d_in[0];
    const int* ei  = (const int*)d_in[1];
    const int* ppi = (const int*)d_in[2];
    const float* sv   = (const float*)d_in[3];
    const float* temb = (const float*)d_in[4];
    const float* iemb = (const float*)d_in[5];
    const float* pemb = (const float*)d_in[6];
    const float* sw   = (const float*)d_in[7];
    const float* sb   = (const float*)d_in[8];
    const float* lng  = (const float*)d_in[9];
    const float* lnb  = (const float*)d_in[10];
    const float* pw   = (const float*)d_in[11];
    const float* pb   = (const float*)d_in[12];
    const float* dw   = (const float*)d_in[13];
    const float* db   = (const float*)d_in[14];
    const float* cw   = (const float*)d_in[15];
    const float* cbp  = (const float*)d_in[16];
    float* out = (float*)d_out;

    // ws: table@0 (2KB) | cnt@2048 (12B) | sprj@4096 (24KB f32)
    //     pfeat@28672 (512x768 bf16 = 768KB) | lists@815104 (3x32768 int = 384KB)
    int*      table = (int*)d_ws;
    int*      cnt   = (int*)((char*)d_ws + 2048);
    float*    sprj  = (float*)((char*)d_ws + 4096);
    ushort_t* pfeat = (ushort_t*)((char*)d_ws + 28672);
    int*      lists = (int*)((char*)d_ws + 815104);

    hipMemsetAsync(table, 0xFF, 512 * sizeof(int), stream);   // all -1
    hipMemsetAsync(cnt, 0x00, 3 * sizeof(int), stream);

    k1<<<130, 256, 0, stream>>>(et, ei, sv, sw, sb, table, sprj, out);
    k2<<<256, 256, 0, stream>>>(et, ei, ppi, temb, iemb, pemb, lng, lnb,
                                table, sprj, pfeat, cnt, lists);
    k3<<<1536, 256, 0, stream>>>(ei, ppi, temb, iemb, pemb, lng, lnb,
                                 pw, pb, dw, db, cw, cbp, sprj, pfeat,
                                 cnt, lists, out);
}

// Round 7
// 155.189 us; speedup vs baseline: 1.7831x; 1.0117x over previous
//
#include <hip/hip_runtime.h>

#define NB 8
#define NS 4096
#define ND 768
#define NT 32768   // NB*NS

typedef float4 f4;
typedef __attribute__((ext_vector_type(8))) short short8;
typedef __attribute__((ext_vector_type(4))) float floatx4;
typedef unsigned short ushort_t;
typedef unsigned int uint_t;

static __device__ __forceinline__ ushort_t f2b(float f) {   // f32 -> bf16 RNE
    union { float f; uint_t u; } v; v.f = f;
    uint_t r = (v.u + 0x7FFFu + ((v.u >> 16) & 1u)) >> 16;
    return (ushort_t)r;
}
static __device__ __forceinline__ f4 ld4(const float* p) { return *(const f4*)p; }

static __device__ __forceinline__ float wred(float v) {
    v += __shfl_xor(v, 32, 64);
    v += __shfl_xor(v, 16, 64);
    v += __shfl_xor(v, 8, 64);
    v += __shfl_xor(v, 4, 64);
    v += __shfl_xor(v, 2, 64);
    v += __shfl_xor(v, 1, 64);
    return v;
}

// ---------------------------------------------------------------------------
// K1 (165 blocks):
//  b<128   : zero d_out (grid-stride), zero cnt (b0), scatter-max parent table
//  b128-133: comb[ty-1][b] = temb[ty] + style_vector[b]@style_w + style_b
//  b134    : head corrections cor1[h][n]=sum_k g*w, cor2[h][n]=sum_k b*w
//  b135-164: Bswz (7680 uint4): bf16 MFMA B-frags; pw 1536 | dw 3072 | cw 3072.
//            Own-half rows (k<768) pre-scaled by ln_g; zero-pad to N=16.
// ---------------------------------------------------------------------------
__global__ __launch_bounds__(256) void k1(
    const int* __restrict__ et, const int* __restrict__ ei,
    const float* __restrict__ sv, const float* __restrict__ sw,
    const float* __restrict__ sb, const float* __restrict__ temb,
    const float* __restrict__ lng, const float* __restrict__ lnb,
    const float* __restrict__ pw, const float* __restrict__ dw,
    const float* __restrict__ cw,
    int* __restrict__ table, int* __restrict__ cnt, float* __restrict__ cors,
    float* __restrict__ comb, uint4* __restrict__ Bswz, float* __restrict__ out)
{
    const int blk = blockIdx.x, tid = threadIdx.x;
    if (blk < 128) {
        const int t = blk * 256 + tid;
        for (int i = t; i < 163840; i += 32768)
            ((f4*)out)[i] = make_float4(0.f, 0.f, 0.f, 0.f);
        if (blk == 0 && tid < 3) cnt[tid] = 0;
        if (et[t] == 1)
            atomicMax(&table[(t >> 12) * 64 + ei[t]], t & (NS - 1));
    } else if (blk < 134) {
        const int lane = tid & 63;
        const int idx = (blk - 128) * 4 + (tid >> 6);    // 0..23
        const int ty = 1 + (idx >> 3), b = idx & 7;
        const float s0 = sv[b*4+0], s1 = sv[b*4+1], s2 = sv[b*4+2], s3 = sv[b*4+3];
        #pragma unroll
        for (int g = 0; g < 3; ++g) {
            int i = g*64 + lane;
            f4 w0 = ((const f4*)sw)[i],     w1 = ((const f4*)sw)[192+i];
            f4 w2 = ((const f4*)sw)[384+i], w3 = ((const f4*)sw)[576+i];
            f4 bb = ((const f4*)sb)[i];
            f4 te = ((const f4*)(temb + ty*ND))[i];
            f4 r;
            r.x = te.x + bb.x + s0*w0.x + s1*w1.x + s2*w2.x + s3*w3.x;
            r.y = te.y + bb.y + s0*w0.y + s1*w1.y + s2*w2.y + s3*w3.y;
            r.z = te.z + bb.z + s0*w0.z + s1*w1.z + s2*w2.z + s3*w3.z;
            r.w = te.w + bb.w + s0*w0.w + s1*w1.w + s2*w2.w + s3*w3.w;
            ((f4*)(comb + idx*ND))[i] = r;
        }
    } else if (blk == 134) {
        const int lane = tid & 63;
        const int h = tid >> 6;                          // 0..3 (3 idle)
        if (h < 3) {
            const int W = (h == 2) ? 4 : 8;
            const float* wsrc = (h == 0) ? pw : (h == 1) ? dw : cw;
            for (int n = 0; n < 16; ++n) {
                float a1 = 0.f, a2 = 0.f;
                if (n < W) {
                    for (int i = 0; i < 12; ++i) {
                        int k = i*64 + lane;
                        float wv = wsrc[k*W + n];
                        a1 += lng[k] * wv;
                        a2 += lnb[k] * wv;
                    }
                }
                a1 = wred(a1); a2 = wred(a2);
                if (lane == 0) { cors[h*16 + n] = a1; cors[48 + h*16 + n] = a2; }
            }
        }
    } else {
        const int e = (blk - 135) * 256 + tid;           // 0..7679
        const int h = (e < 1536) ? 0 : (e < 4608) ? 1 : 2;
        const int base = (h == 0) ? 0 : (h == 1) ? 1536 : 4608;
        const int idx = e - base;                        // pw:0..1535 dw/cw:0..3071
        const int s = idx >> 6, l = idx & 63;
        const int n = l & 15, kq = l >> 4;
        const int W = (h == 2) ? 4 : 8;
        const float* wsrc = (h == 0) ? pw : (h == 1) ? dw : cw;
        ushort_t v[8];
        #pragma unroll
        for (int j = 0; j < 8; ++j) {
            int k = 32*s + 8*kq + j;
            float val = 0.f;
            if (n < W) {
                float sc = (k < 768) ? lng[k] : 1.f;     // own-half g-scaled
                val = wsrc[k*W + n] * sc;
            }
            v[j] = f2b(val);
        }
        uint4 q;
        q.x = (uint_t)v[0] | ((uint_t)v[1] << 16);
        q.y = (uint_t)v[2] | ((uint_t)v[3] << 16);
        q.z = (uint_t)v[4] | ((uint_t)v[5] << 16);
        q.w = (uint_t)v[6] | ((uint_t)v[7] << 16);
        Bswz[e] = q;
    }
}

// ---------------------------------------------------------------------------
// K2: blocks 0..127  : parent panel feats (LN'd bf16) -> pfeat[b*64+slot]
//     blocks 128..255: per-type token lists (wave-aggregated ballot atomics)
// ---------------------------------------------------------------------------
__global__ __launch_bounds__(256) void k2(
    const int* __restrict__ et, const int* __restrict__ ei, const int* __restrict__ ppi,
    const float* __restrict__ iemb, const float* __restrict__ pemb,
    const float* __restrict__ lng, const float* __restrict__ lnb,
    const int* __restrict__ table, const float* __restrict__ comb,
    ushort_t* __restrict__ pfeat, int* __restrict__ cnt, int* __restrict__ lists)
{
    if (blockIdx.x < 128) {
        const int lane = threadIdx.x & 63;
        const int slot = blockIdx.x * 4 + (threadIdx.x >> 6);   // 0..511
        const int pp = table[slot];
        if (pp < 0) return;                                     // wave-uniform
        const int b = slot >> 6;
        const int ptok = b * NS + pp;
        const float* ie = iemb + ei[ptok] * ND;
        const float* pe = pemb + ppi[ptok] * ND;
        const float* cm = comb + b * ND;                        // ty=1 row

        f4 x[3]; float s1 = 0.f;
        #pragma unroll
        for (int g = 0; g < 3; ++g) {
            int i = g*64 + lane;
            f4 a = ((const f4*)cm)[i], c = ((const f4*)ie)[i], d = ((const f4*)pe)[i];
            x[g].x = a.x + c.x + d.x;
            x[g].y = a.y + c.y + d.y;
            x[g].z = a.z + c.z + d.z;
            x[g].w = a.w + c.w + d.w;
            s1 += x[g].x + x[g].y + x[g].z + x[g].w;
        }
        float mu = wred(s1) * (1.f/ND);
        float s2 = 0.f;
        #pragma unroll
        for (int g = 0; g < 3; ++g) {
            float dx = x[g].x-mu, dy = x[g].y-mu, dz = x[g].z-mu, dw_ = x[g].w-mu;
            s2 += dx*dx + dy*dy + dz*dz + dw_*dw_;
        }
        float rs = rsqrtf(wred(s2) * (1.f/ND) + 1e-5f);
        ushort_t* dst = pfeat + (size_t)slot * ND;
        #pragma unroll
        for (int g = 0; g < 3; ++g) {
            int i = g*64 + lane;
            f4 gg = ((const f4*)lng)[i], bb = ((const f4*)lnb)[i];
            ushort_t r0 = f2b((x[g].x-mu)*rs*gg.x + bb.x);
            ushort_t r1 = f2b((x[g].y-mu)*rs*gg.y + bb.y);
            ushort_t r2 = f2b((x[g].z-mu)*rs*gg.z + bb.z);
            ushort_t r3 = f2b((x[g].w-mu)*rs*gg.w + bb.w);
            *(uint2*)(dst + 4*i) = make_uint2((uint_t)r0 | ((uint_t)r1 << 16),
                                              (uint_t)r2 | ((uint_t)r3 << 16));
        }
    } else {
        const int t = (blockIdx.x - 128) * 256 + threadIdx.x;
        const int lane = threadIdx.x & 63;
        const int ty = et[t];
        const bool vld = (ty >= 2) && (table[(t >> 12) * 64 + ppi[t]] >= 0);
        #pragma unroll
        for (int i = 1; i <= 3; ++i) {
            bool p = (i == 1) ? (ty == 1) : (ty == i && vld);
            unsigned long long mask = __ballot(p);
            if (mask == 0ull) continue;
            int leader = __ffsll((long long)mask) - 1;
            int base = 0;
            if (lane == leader)
                base = atomicAdd(&cnt[i - 1], __popcll(mask));
            base = __shfl(base, leader, 64);
            if (p) {
                int prefix = __popcll(mask & ((1ull << lane) - 1ull));
                lists[(i - 1) * NT + base + prefix] = t;
            }
        }
    }
}

// ---------------------------------------------------------------------------
// K3: MFMA heads, no LDS, single pass. Raw x fed to MFMA against g-scaled
// B-fragments (precomputed in ws); LN folded in algebraically:
//   out_n = rs*(acc_own_n - mu*cor1_n) + cor2_n + acc_parent_n + bias_n
// ---------------------------------------------------------------------------
__global__ __launch_bounds__(256) void k3(
    const int* __restrict__ ei, const int* __restrict__ ppi,
    const float* __restrict__ iemb, const float* __restrict__ pemb,
    const float* __restrict__ pb, const float* __restrict__ db,
    const float* __restrict__ cb,
    const float* __restrict__ comb, const ushort_t* __restrict__ pfeat,
    const float* __restrict__ cors, const uint4* __restrict__ Bswz,
    const int* __restrict__ cnt, const int* __restrict__ lists,
    float* __restrict__ out)
{
    const int ty = (blockIdx.x >> 9) + 1;            // 1,2,3 (wave-uniform)
    const int chunk = blockIdx.x & 511;
    const int cn = cnt[ty - 1];
    if (chunk * 64 >= cn) return;
    const int lane = threadIdx.x & 63;
    const int gbase = chunk * 64 + (threadIdx.x >> 6) * 16;
    if (gbase >= cn) return;

    const int W = (ty == 3) ? 4 : 8;
    const float* bias = (ty == 1) ? pb : (ty == 2) ? db : cb;
    const uint4* bsw = Bswz + ((ty == 1) ? 0 : (ty == 2) ? 1536 : 4608);
    const int* list = lists + (ty - 1) * NT;

    const int m = lane & 15;                         // token row in tile
    const int kq = lane >> 4;
    const int koff = kq * 8;
    const int slot = min(gbase + m, cn - 1);
    const int tl = list[slot];
    const int b = tl >> 12;
    const int pidx = ppi[tl];
    const float* cm_p = comb + ((ty - 1) * 8 + b) * ND;
    const float* ie_p = iemb + ei[tl] * ND;
    const float* pe_p = pemb + pidx * ND;
    const ushort_t* pf_p = pfeat + (size_t)(b * 64 + pidx) * ND;

    floatx4 accO = {0.f, 0.f, 0.f, 0.f};
    floatx4 accP = {0.f, 0.f, 0.f, 0.f};
    float sum = 0.f, sq = 0.f;
    #pragma unroll
    for (int s = 0; s < 24; ++s) {
        const int d0 = 32*s + koff;
        f4 c0 = ld4(cm_p + d0), c1 = ld4(cm_p + d0 + 4);
        f4 i0 = ld4(ie_p + d0), i1 = ld4(ie_p + d0 + 4);
        f4 p0 = ld4(pe_p + d0), p1 = ld4(pe_p + d0 + 4);
        float x0 = c0.x + i0.x + p0.x, x1 = c0.y + i0.y + p0.y;
        float x2 = c0.z + i0.z + p0.z, x3 = c0.w + i0.w + p0.w;
        float x4 = c1.x + i1.x + p1.x, x5 = c1.y + i1.y + p1.y;
        float x6 = c1.z + i1.z + p1.z, x7 = c1.w + i1.w + p1.w;
        sum += (x0+x1)+(x2+x3)+(x4+x5)+(x6+x7);
        sq  += (x0*x0+x1*x1)+(x2*x2+x3*x3)+(x4*x4+x5*x5)+(x6*x6+x7*x7);
        short8 a;
        a[0]=(short)f2b(x0); a[1]=(short)f2b(x1); a[2]=(short)f2b(x2); a[3]=(short)f2b(x3);
        a[4]=(short)f2b(x4); a[5]=(short)f2b(x5); a[6]=(short)f2b(x6); a[7]=(short)f2b(x7);
        short8 bO = *(const short8*)&bsw[s*64 + lane];
        accO = __builtin_amdgcn_mfma_f32_16x16x32_bf16(a, bO, accO, 0, 0, 0);
        if (ty != 1) {
            short8 aP = *(const short8*)(pf_p + 32*s + koff);
            short8 bP = *(const short8*)&bsw[(24 + s)*64 + lane];
            accP = __builtin_amdgcn_mfma_f32_16x16x32_bf16(aP, bP, accP, 0, 0, 0);
        }
    }
    // per-token stats: lanes {m, m+16, m+32, m+48} -> all hold token m's totals
    sum += __shfl_xor(sum, 16, 64); sum += __shfl_xor(sum, 32, 64);
    sq  += __shfl_xor(sq , 16, 64); sq  += __shfl_xor(sq , 32, 64);
    const float mu = sum * (1.f/ND);
    const float rs = rsqrtf(sq * (1.f/ND) - mu*mu + 1e-5f);

    const int n = lane & 15;
    const float co1 = cors[(ty-1)*16 + n];
    const float co2 = cors[48 + (ty-1)*16 + n];
    const float bv  = (n < W) ? bias[n] : 0.f;
    const long obase = (ty == 1) ? 0L : (ty == 2) ? (long)NT*8 : (long)NT*16;
    #pragma unroll
    for (int r = 0; r < 4; ++r) {
        const int row = kq*4 + r;
        const float mur = __shfl(mu, row, 64);       // lane 'row' holds token row
        const float rsr = __shfl(rs, row, 64);
        const int rslot = gbase + row;
        if (n < W && rslot < cn) {
            int tr = list[rslot];
            out[obase + (long)tr * W + n] = rsr*(accO[r] - mur*co1) + co2 + accP[r] + bv;
        }
    }
}

extern "C" void kernel_launch(void* const* d_in, const int* in_sizes, int n_in,
                              void* d_out, int out_size, void* d_ws, size_t ws_size,
                              hipStream_t stream) {
    const int* et  = (const int*)d_in[0];
    const int* ei  = (const int*)d_in[1];
    const int* ppi = (const int*)d_in[2];
    const float* sv   = (const float*)d_in[3];
    const float* temb = (const float*)d_in[4];
    const float* iemb = (const float*)d_in[5];
    const float* pemb = (const float*)d_in[6];
    const float* sw   = (const float*)d_in[7];
    const float* sb   = (const float*)d_in[8];
    const float* lng  = (const float*)d_in[9];
    const float* lnb  = (const float*)d_in[10];
    const float* pw   = (const float*)d_in[11];
    const float* pb   = (const float*)d_in[12];
    const float* dw   = (const float*)d_in[13];
    const float* db   = (const float*)d_in[14];
    const float* cw   = (const float*)d_in[15];
    const float* cbp  = (const float*)d_in[16];
    float* out = (float*)d_out;

    // ws: table@0 (2KB) | cnt@2048 | cors@2304 (96 f32) | comb@4096 (24x768 f32)
    //     pfeat@81920 (512x768 bf16) | lists@868352 (3x32768 int)
    //     Bswz@1261568 (7680 uint4 = 120KB)
    int*      table = (int*)d_ws;
    int*      cnt   = (int*)((char*)d_ws + 2048);
    float*    cors  = (float*)((char*)d_ws + 2304);
    float*    comb  = (float*)((char*)d_ws + 4096);
    ushort_t* pfeat = (ushort_t*)((char*)d_ws + 81920);
    int*      lists = (int*)((char*)d_ws + 868352);
    uint4*    Bswz  = (uint4*)((char*)d_ws + 1261568);

    hipMemsetAsync(table, 0xFF, 512 * sizeof(int), stream);   // all -1

    k1<<<165, 256, 0, stream>>>(et, ei, sv, sw, sb, temb, lng, lnb,
                                pw, dw, cw, table, cnt, cors, comb, Bswz, out);
    k2<<<256, 256, 0, stream>>>(et, ei, ppi, iemb, pemb, lng, lnb,
                                table, comb, pfeat, cnt, lists);
    k3<<<1536, 256, 0, stream>>>(ei, ppi, iemb, pemb, pb, db, cbp,
                                 comb, pfeat, cors, Bswz, cnt, lists, out);
}